// Round 13
// baseline (439.048 us; speedup 1.0000x reference)
//
#include <hip/hip_runtime.h>

#define HD 128  // hidden/feature dim (fixed by problem)
// fp8 e4m3 pre-scale: T1 rms ~2e-3, T2 rms ~8e-5 underflow e4m3's 2^-9 subnormal
// floor unscaled (round-12 failure: T2 -> all-zero -> output exactly 0). S=2^13
// puts T1~16, T2~0.7 in the normal range; clip at 448 = 27 sigma (never).
#define FP8_SCALE 8192.0f
#define FP8_INV   (1.0f / 8192.0f)

typedef _Float16 f16x8 __attribute__((ext_vector_type(8)));
typedef float f32x4 __attribute__((ext_vector_type(4)));
typedef float f32x2 __attribute__((ext_vector_type(2)));

static __device__ __forceinline__ unsigned char f32_to_fp8(float v) {
  // e4m3 (OCP), RNE, saturating; pack (v,v) into low word, take byte 0
  return (unsigned char)(__builtin_amdgcn_cvt_pk_fp8_f32(v, v, 0, false) & 0xff);
}

// sparse role (role=1) occupies every k-th block: positions q*k, q<S.
__device__ __forceinline__ void role_map(int bi, int S, int k, int& role, int& rid) {
  int q = bi / k, rem = bi - q * k;
  if (rem == 0 && q < S) { role = 1; rid = q; }
  else { role = 0; int na = q + (rem ? 1 : 0); if (na > S) na = S; rid = bi - na; }
}

// ---------------- weight convert: fp32 [k][n] -> f16 MFMA-fragment order ----------
__global__ void k_wcvt(const float* __restrict__ w0, const float* __restrict__ w1,
                       const float* __restrict__ w2, const float* __restrict__ w3,
                       _Float16* __restrict__ Wf) {
  int m = blockIdx.x >> 3;
  const float* Wg = (m == 0) ? w0 : (m == 1) ? w1 : (m == 2) ? w2 : w3;
  int idx0 = (blockIdx.x & 7) * 2048 + threadIdx.x * 8;
  float4 u0 = *(const float4*)(Wg + idx0);
  float4 u1 = *(const float4*)(Wg + idx0 + 4);
  int k = idx0 >> 7, n0 = idx0 & 127;
  int kc = k >> 5, q2 = (k >> 3) & 3, j = k & 7;
  _Float16* dst = Wf + (size_t)m * 16384;
  float vv[8] = {u0.x, u0.y, u0.z, u0.w, u1.x, u1.y, u1.z, u1.w};
  #pragma unroll
  for (int d = 0; d < 8; ++d) {
    int n = n0 + d;
    dst[(size_t)(((n >> 4) * 4 + kc) * 64 + 16 * q2 + (n & 15)) * 8 + j] = (_Float16)vv[d];
  }
}

// ---------------- deg role: NON-returning atomics (fire-and-forget) ---------------
__device__ __forceinline__ void deg_core(int rid, int degB,
    const int* __restrict__ ei0, const int* __restrict__ ei1, int E, int N,
    int* __restrict__ deg2) {
  int g = (rid >= degB);
  int cb = rid - g * degB;
  const int* rows = g ? ei1 : ei0;
  int* deg = deg2 + g * N;
  int base = (cb * 256 + threadIdx.x) * 4;
  if (base + 3 < E) {
    int4 r = *(const int4*)(rows + base);
    atomicAdd(&deg[r.x], 1);
    atomicAdd(&deg[r.y], 1);
    atomicAdd(&deg[r.z], 1);
    atomicAdd(&deg[r.w], 1);
  } else {
    for (int e = base; e < E; ++e) atomicAdd(&deg[rows[e]], 1);
  }
}

// ---------------- CSR fill role: returning atomic on cnt[] -----------------------
__device__ __forceinline__ void fill_core(int rid, int fillB,
    const int* __restrict__ ei0, const int* __restrict__ ei1, int E, int N,
    const int* __restrict__ offs, const int* __restrict__ partials,
    int* __restrict__ cnt, unsigned short* __restrict__ csr_col) {
  int g = (rid >= fillB);
  int cb = rid - g * fillB;
  const int* eg = (g ? ei1 : ei0);
  const int* ob = offs + g * N;
  int gN = g * N;
  int base = (cb * 256 + threadIdx.x) * 4;
  if (base + 3 < E) {
    int4 r = *(const int4*)(eg + base);
    int4 c = *(const int4*)(eg + E + base);
    int p0 = ob[r.x] + partials[(gN + r.x) >> 8] + atomicAdd(&cnt[gN + r.x], 1);
    int p1 = ob[r.y] + partials[(gN + r.y) >> 8] + atomicAdd(&cnt[gN + r.y], 1);
    int p2 = ob[r.z] + partials[(gN + r.z) >> 8] + atomicAdd(&cnt[gN + r.z], 1);
    int p3 = ob[r.w] + partials[(gN + r.w) >> 8] + atomicAdd(&cnt[gN + r.w], 1);
    csr_col[p0] = (unsigned short)c.x;
    csr_col[p1] = (unsigned short)c.y;
    csr_col[p2] = (unsigned short)c.z;
    csr_col[p3] = (unsigned short)c.w;
  } else {
    for (int e = base; e < E; ++e) {
      int r = eg[e];
      int p = ob[r] + partials[(gN + r) >> 8] + atomicAdd(&cnt[gN + r], 1);
      csr_col[p] = (unsigned short)eg[E + e];
    }
  }
}

// ---------------- GEMM role: C = (A @ Wfrag + b) * dis[row]; FP8(scaled) or f16 ---
template<bool FP8>
__device__ __forceinline__ void gemm_core(_Float16* lds, int bi,
    const _Float16* __restrict__ Ab, const _Float16* __restrict__ Wf,
    const float* __restrict__ bias, const float* __restrict__ scale,
    void* __restrict__ Cv, int Ntot) {
  const int tid = threadIdx.x;
  #pragma unroll
  for (int i = 0; i < 8; ++i)
    *(float4*)&lds[tid * 8 + i * 2048] = *(const float4*)&Wf[tid * 8 + i * 2048];
  __syncthreads();

  const int lane = tid & 63, wave = tid >> 6;
  const int n16 = lane & 15, q = lane >> 4;
  const int rowbase = bi * 128 + wave * 32;

  int arow[2];
  #pragma unroll
  for (int t = 0; t < 2; ++t) {
    int r = rowbase + 16 * t + n16;
    arow[t] = (r < Ntot) ? r : (Ntot - 1);
  }
  f32x4 acc[2][8];
  #pragma unroll
  for (int t = 0; t < 2; ++t)
    #pragma unroll
    for (int nt = 0; nt < 8; ++nt) acc[t][nt] = (f32x4){0.f, 0.f, 0.f, 0.f};

  #pragma unroll
  for (int kc = 0; kc < 4; ++kc) {
    f16x8 a[2];
    #pragma unroll
    for (int t = 0; t < 2; ++t)
      a[t] = *(const f16x8*)(Ab + (size_t)arow[t] * HD + kc * 32 + q * 8);
    #pragma unroll
    for (int nt = 0; nt < 8; ++nt) {
      f16x8 b = *(const f16x8*)&lds[(size_t)((nt * 4 + kc) * 64 + lane) * 8];
      #pragma unroll
      for (int t = 0; t < 2; ++t)
        acc[t][nt] = __builtin_amdgcn_mfma_f32_16x16x32_f16(a[t], b, acc[t][nt], 0, 0, 0);
    }
  }
  float bv[8];
  #pragma unroll
  for (int nt = 0; nt < 8; ++nt) bv[nt] = bias[nt * 16 + n16];
  #pragma unroll
  for (int t = 0; t < 2; ++t) {
    #pragma unroll
    for (int r = 0; r < 4; ++r) {
      int row = rowbase + 16 * t + 4 * q + r;
      if (row < Ntot) {
        float s = scale[row];
        #pragma unroll
        for (int nt = 0; nt < 8; ++nt) {
          float v = (acc[t][nt][r] + bv[nt]) * s;
          if (FP8)
            ((unsigned char*)Cv)[(size_t)row * HD + nt * 16 + n16] =
                f32_to_fp8(v * FP8_SCALE);
          else
            ((_Float16*)Cv)[(size_t)row * HD + nt * 16 + n16] = (_Float16)v;
        }
      }
    }
  }
}

// ---------------- chained enc1+enc2 (row-local; act via wave-private LDS) ---------
__device__ __forceinline__ void chain_core(_Float16* act, int bi,
    const float* __restrict__ x0, const float* __restrict__ x1,
    const _Float16* __restrict__ Wf0, const _Float16* __restrict__ Wf1,
    const float* __restrict__ b1, const float* __restrict__ b2,
    _Float16* __restrict__ H, int N, int Ntot) {
  const int tid = threadIdx.x;
  const int lane = tid & 63, wave = tid >> 6;
  const int n16 = lane & 15, q = lane >> 4;
  const int rowbase = bi * 128 + wave * 32;
  _Float16* wact = act + wave * 4352;   // 32 rows x 136 f16

  int arow[2];
  #pragma unroll
  for (int t = 0; t < 2; ++t) {
    int r = rowbase + 16 * t + n16;
    arow[t] = (r < Ntot) ? r : (Ntot - 1);
  }
  f32x4 acc[2][8];
  #pragma unroll
  for (int t = 0; t < 2; ++t)
    #pragma unroll
    for (int nt = 0; nt < 8; ++nt) acc[t][nt] = (f32x4){0.f, 0.f, 0.f, 0.f};

  // layer 1: x -> relu(x@W1+b1) -> wave-private LDS
  #pragma unroll
  for (int kc = 0; kc < 4; ++kc) {
    f16x8 a[2];
    #pragma unroll
    for (int t = 0; t < 2; ++t) {
      int r = arow[t];
      const float* src = (r < N) ? (x0 + (size_t)r * HD) : (x1 + (size_t)(r - N) * HD);
      float4 u0 = *(const float4*)(src + kc * 32 + q * 8);
      float4 u1 = *(const float4*)(src + kc * 32 + q * 8 + 4);
      union { _Float16 h[8]; f16x8 v; } tmp;
      tmp.h[0] = (_Float16)u0.x; tmp.h[1] = (_Float16)u0.y;
      tmp.h[2] = (_Float16)u0.z; tmp.h[3] = (_Float16)u0.w;
      tmp.h[4] = (_Float16)u1.x; tmp.h[5] = (_Float16)u1.y;
      tmp.h[6] = (_Float16)u1.z; tmp.h[7] = (_Float16)u1.w;
      a[t] = tmp.v;
    }
    #pragma unroll
    for (int nt = 0; nt < 8; ++nt) {
      f16x8 b = *(const f16x8*)&Wf0[(size_t)((nt * 4 + kc) * 64 + lane) * 8];
      #pragma unroll
      for (int t = 0; t < 2; ++t)
        acc[t][nt] = __builtin_amdgcn_mfma_f32_16x16x32_f16(a[t], b, acc[t][nt], 0, 0, 0);
    }
  }
  {
    float bv[8];
    #pragma unroll
    for (int nt = 0; nt < 8; ++nt) bv[nt] = b1[nt * 16 + n16];
    #pragma unroll
    for (int t = 0; t < 2; ++t)
      #pragma unroll
      for (int r = 0; r < 4; ++r)
        #pragma unroll
        for (int nt = 0; nt < 8; ++nt)
          wact[(16 * t + 4 * q + r) * 136 + nt * 16 + n16] =
              (_Float16)fmaxf(acc[t][nt][r] + bv[nt], 0.f);
  }

  // layer 2: h1 -> h1@W2+b2 (no relu)
  #pragma unroll
  for (int t = 0; t < 2; ++t)
    #pragma unroll
    for (int nt = 0; nt < 8; ++nt) acc[t][nt] = (f32x4){0.f, 0.f, 0.f, 0.f};
  #pragma unroll
  for (int kc = 0; kc < 4; ++kc) {
    f16x8 a[2];
    #pragma unroll
    for (int t = 0; t < 2; ++t)
      a[t] = *(const f16x8*)&wact[(16 * t + n16) * 136 + kc * 32 + q * 8];
    #pragma unroll
    for (int nt = 0; nt < 8; ++nt) {
      f16x8 b = *(const f16x8*)&Wf1[(size_t)((nt * 4 + kc) * 64 + lane) * 8];
      #pragma unroll
      for (int t = 0; t < 2; ++t)
        acc[t][nt] = __builtin_amdgcn_mfma_f32_16x16x32_f16(a[t], b, acc[t][nt], 0, 0, 0);
    }
  }
  {
    float bv[8];
    #pragma unroll
    for (int nt = 0; nt < 8; ++nt) bv[nt] = b2[nt * 16 + n16];
    #pragma unroll
    for (int t = 0; t < 2; ++t)
      #pragma unroll
      for (int r = 0; r < 4; ++r) {
        int row = rowbase + 16 * t + 4 * q + r;
        if (row < Ntot)
          #pragma unroll
          for (int nt = 0; nt < 8; ++nt)
            H[(size_t)row * HD + nt * 16 + n16] = (_Float16)(acc[t][nt][r] + bv[nt]);
      }
  }
}

// ---------------- aggregate core (scaled fp8 T): out = relu(dis/S * sum T) --------
template<bool POOL>
__device__ __forceinline__ void agg_core(float* red, int rid,
    const unsigned char* __restrict__ T8, const int* __restrict__ offs,
    const int* __restrict__ partials, const unsigned short* __restrict__ csr_col,
    const float* __restrict__ dis, _Float16* __restrict__ out,
    float* __restrict__ poolrep, int N, int Ntot, int Etot) {
  const int lane = threadIdx.x & 63;
  const int wave = threadIdx.x >> 6;
  const int gw = rid * 4 + wave;
  const int sub = lane >> 4, c16 = lane & 15;

  float ax[8];
  #pragma unroll
  for (int j = 0; j < 8; ++j) ax[j] = 0.f;

  const int beg = offs[gw] + partials[gw >> 8];
  const int end = (gw + 1 == Ntot) ? Etot : (offs[gw + 1] + partials[(gw + 1) >> 8]);
  const uint2* Tg = (const uint2*)(T8 + (size_t)(gw >= N ? N : 0) * HD);
  for (int e = beg; e < end; e += 16) {
    uint2 v[4];
    #pragma unroll
    for (int gp = 0; gp < 4; ++gp) {
      v[gp] = make_uint2(0, 0);            // fp8 0x00 == +0.0
      if (e + 4 * gp < end) {              // wave-uniform
        int eg = e + 4 * gp + sub;
        bool valid = (eg < end);
        int ce = valid ? eg : (end - 1);
        int col = csr_col[ce];
        uint2 tv = Tg[(size_t)col * 16 + c16];
        if (valid) v[gp] = tv;
      }
    }
    #pragma unroll
    for (int gp = 0; gp < 4; ++gp) {
      f32x2 p0 = __builtin_amdgcn_cvt_pk_f32_fp8((int)v[gp].x, false);
      f32x2 p1 = __builtin_amdgcn_cvt_pk_f32_fp8((int)v[gp].x, true);
      f32x2 p2 = __builtin_amdgcn_cvt_pk_f32_fp8((int)v[gp].y, false);
      f32x2 p3 = __builtin_amdgcn_cvt_pk_f32_fp8((int)v[gp].y, true);
      ax[0] += p0.x; ax[1] += p0.y;
      ax[2] += p1.x; ax[3] += p1.y;
      ax[4] += p2.x; ax[5] += p2.y;
      ax[6] += p3.x; ax[7] += p3.y;
    }
  }

  #pragma unroll
  for (int j = 0; j < 8; ++j) {
    ax[j] += __shfl_xor(ax[j], 32, 64);
    ax[j] += __shfl_xor(ax[j], 16, 64);
  }
  float dr = dis[gw] * FP8_INV;            // undo the fp8 pre-scale
  #pragma unroll
  for (int j = 0; j < 8; ++j) ax[j] = fmaxf(ax[j] * dr, 0.f);

  if (!POOL) {
    if (sub == 0) {                        // h1 stays f16 (feeds conv2 MFMA A)
      union { uint4 u; _Float16 h[8]; } o;
      #pragma unroll
      for (int j = 0; j < 8; ++j) o.h[j] = (_Float16)ax[j];
      ((uint4*)out)[(size_t)gw * 16 + c16] = o.u;
    }
  } else {
    if (sub == 0) {
      *(float4*)&red[wave * 128 + c16 * 8]     = make_float4(ax[0], ax[1], ax[2], ax[3]);
      *(float4*)&red[wave * 128 + c16 * 8 + 4] = make_float4(ax[4], ax[5], ax[6], ax[7]);
    }
    __syncthreads();
    int t = threadIdx.x;
    if (t < 128) {
      float s = red[t] + red[128 + t] + red[256 + t] + red[384 + t];
      int g = (rid * 4 >= N) ? 1 : 0;      // N % 4 == 0: block never spans graphs
      atomicAdd(&poolrep[(size_t)((rid & 15) * 2 + g) * 128 + t], s);
    }
  }
}

// ---------------- D1: deg (non-returning) aux || chained enc1+enc2 ----------------
__global__ __launch_bounds__(256, 4) void k_d1(
    const float* __restrict__ x0, const float* __restrict__ x1,
    const _Float16* __restrict__ Wf, const float* __restrict__ b1,
    const float* __restrict__ b2, _Float16* __restrict__ H,
    const int* __restrict__ ei0, const int* __restrict__ ei1, int E, int N, int Ntot,
    int* __restrict__ deg2, int G, int A, int degB) {
  __shared__ _Float16 act[4 * 4352];  // 34.8 KB
  int role, rid;
  role_map(blockIdx.x, G, (A + G) / G, role, rid);  // sparse = chain (every 3rd)
  if (role == 1)
    chain_core(act, rid, x0, x1, Wf, Wf + 16384, b1, b2, H, N, Ntot);
  else
    deg_core(rid, degB, ei0, ei1, E, N, deg2);
}

// ---------------- D2: per-block deg scan + dis; last block scans partials ---------
__global__ __launch_bounds__(256, 2) void k_scan(
    const int* __restrict__ deg2, int* __restrict__ offs, int* __restrict__ partials,
    float* __restrict__ dis, int Ntot, int scanB, int* __restrict__ ctr) {
  __shared__ int s[512];
  __shared__ int lastFlag;
  int rid = blockIdx.x, t = threadIdx.x;
  int i = rid * 256 + t;
  int v = (i < Ntot) ? deg2[i] : 0;
  s[t] = v;
  __syncthreads();
  #pragma unroll
  for (int off = 1; off < 256; off <<= 1) {
    int x = (t >= off) ? s[t - off] : 0;
    __syncthreads();
    s[t] += x;
    __syncthreads();
  }
  if (i < Ntot) {
    offs[i] = s[t] - v;
    dis[i] = (v > 0) ? (1.0f / sqrtf((float)v)) : 0.0f;
  }
  if (t == 255) partials[rid] = s[255];
  __syncthreads();
  if (t == 0) {
    __threadfence();
    lastFlag = (atomicAdd(ctr, 1) == scanB - 1);
  }
  __syncthreads();
  if (lastFlag) {
    __threadfence();
    volatile int* vp = partials;
    int P = scanB;
    int v0 = (t < P) ? vp[t] : 0;
    int v1 = (t + 256 < P) ? vp[t + 256] : 0;
    __syncthreads();
    s[t] = v0;
    s[t + 256] = v1;
    __syncthreads();
    #pragma unroll
    for (int off = 1; off < 256; off <<= 1) {
      int x0 = (t >= off) ? s[t - off] : 0;
      int x1 = (t >= off) ? s[256 + t - off] : 0;
      __syncthreads();
      s[t] += x0;
      s[256 + t] += x1;
      __syncthreads();
    }
    int tot0 = s[255];
    if (t < P) partials[t] = s[t] - v0;
    if (t + 256 < P) partials[t + 256] = s[256 + t] + tot0 - v1;
  }
}

// ---------------- D3: conv1 both (sparse, scaled-fp8 out) || CSR fill both --------
__global__ __launch_bounds__(256, 4) void k_conv1_fill(
    const _Float16* __restrict__ Ain, const _Float16* __restrict__ Wf,
    const float* __restrict__ bias, const float* __restrict__ dis,
    unsigned char* __restrict__ Cout, int Ntot, int G,
    const int* __restrict__ ei0, const int* __restrict__ ei1, int E, int N,
    const int* __restrict__ offs, const int* __restrict__ partials,
    int* __restrict__ cnt, unsigned short* __restrict__ csr_col, int fillB) {
  __shared__ _Float16 lds[16384];
  int role, rid;
  role_map(blockIdx.x, G, 3, role, rid);  // sparse = gemm (2*fillB + G blocks, fillB==G)
  if (role == 1)
    gemm_core<true>(lds, rid, Ain, Wf, bias, dis, Cout, Ntot);
  else
    fill_core(rid, fillB, ei0, ei1, E, N, offs, partials, cnt, csr_col);
}

// ---------------- D4: aggregate both graphs (fp8 in, f16 out; high occ) -----------
__global__ __launch_bounds__(256) void k_agg(
    const unsigned char* __restrict__ T8, const int* __restrict__ offs,
    const int* __restrict__ partials, const unsigned short* __restrict__ csr_col,
    const float* __restrict__ dis, _Float16* __restrict__ out, int N, int Ntot, int Etot) {
  agg_core<false>(nullptr, blockIdx.x, T8, offs, partials, csr_col, dis,
                  out, nullptr, N, Ntot, Etot);
}

// ---------------- D5: conv2 GEMM both graphs (scaled-fp8 out, standalone) ---------
__global__ __launch_bounds__(256, 4) void k_gemm(
    const _Float16* __restrict__ Ain, const _Float16* __restrict__ Wf,
    const float* __restrict__ bias, const float* __restrict__ dis,
    unsigned char* __restrict__ Cout, int Ntot) {
  __shared__ _Float16 lds[16384];
  gemm_core<true>(lds, blockIdx.x, Ain, Wf, bias, dis, Cout, Ntot);
}

// ---------------- D6: aggregate + pool both graphs (fp8 in; high occ) -------------
__global__ __launch_bounds__(256) void k_agg_pool(
    const unsigned char* __restrict__ T8, const int* __restrict__ offs,
    const int* __restrict__ partials, const unsigned short* __restrict__ csr_col,
    const float* __restrict__ dis, float* __restrict__ poolrep,
    int N, int Ntot, int Etot) {
  __shared__ float red[512];
  agg_core<true>(red, blockIdx.x, T8, offs, partials, csr_col, dis,
                 nullptr, poolrep, N, Ntot, Etot);
}

// ---------------- final similarity MLP (tiny, fp32) ----------------
__global__ void k_final(const float* __restrict__ poolrep,
                        const float* __restrict__ W1, const float* __restrict__ b1,
                        const float* __restrict__ W2, const float* __restrict__ b2,
                        float* __restrict__ out, float invN) {
  __shared__ float cs[512];
  __shared__ float red[2];
  int t = threadIdx.x;  // 128 threads
  float g1 = 0.f, g2 = 0.f;
  #pragma unroll
  for (int r = 0; r < 16; ++r) {
    g1 += poolrep[r * 256 + t];
    g2 += poolrep[r * 256 + 128 + t];
  }
  g1 *= invN;
  g2 *= invN;
  cs[t] = g1;
  cs[128 + t] = g2;
  cs[256 + t] = fabsf(g1 - g2);
  cs[384 + t] = g1 * g2;
  __syncthreads();
  float acc = b1[t];
  #pragma unroll 8
  for (int i = 0; i < 512; ++i) acc = fmaf(cs[i], W1[(size_t)i * HD + t], acc);
  float h = fmaxf(acc, 0.f);
  float v = h * W2[t];
  #pragma unroll
  for (int off = 32; off > 0; off >>= 1) v += __shfl_down(v, off, 64);
  if ((t & 63) == 0) red[t >> 6] = v;
  __syncthreads();
  if (t == 0) out[0] = red[0] + red[1] + b2[0];
}

extern "C" void kernel_launch(void* const* d_in, const int* in_sizes, int n_in,
                              void* d_out, int out_size, void* d_ws, size_t ws_size,
                              hipStream_t stream) {
  const float* x1     = (const float*)d_in[0];
  const int*   ei1    = (const int*)d_in[1];
  const float* x2     = (const float*)d_in[2];
  const int*   ei2    = (const int*)d_in[3];
  const float* W_in[4] = {(const float*)d_in[4], (const float*)d_in[6],
                          (const float*)d_in[8], (const float*)d_in[10]};
  const float* B_in[4] = {(const float*)d_in[5], (const float*)d_in[7],
                          (const float*)d_in[9], (const float*)d_in[11]};
  const float* sim_w1 = (const float*)d_in[12];
  const float* sim_b1 = (const float*)d_in[13];
  const float* sim_w2 = (const float*)d_in[14];
  const float* sim_b2 = (const float*)d_in[15];

  const int N = in_sizes[0] / HD;
  const int E = in_sizes[1] / 2;
  const int Ntot = 2 * N;

  // workspace layout (16B-aligned chunks first)
  _Float16* sp = (_Float16*)d_ws;
  _Float16* bufA = sp; sp += (size_t)Ntot * HD;   // H (enc out)
  _Float16* bufC = sp; sp += (size_t)Ntot * HD;   // h1 (agg1 out)
  unsigned char* bufT8 = (unsigned char*)sp;      // T1 then T2 (scaled fp8)
  sp += (size_t)Ntot * HD / 2;
  _Float16* WfB  = sp; sp += 4 * 16384;           // enc1,enc2,conv1,conv2 frag f16
  float* fp = (float*)sp;
  float* dis     = fp; fp += Ntot;
  float* poolrep = fp; fp += 16 * 256;            // zeroed with ctrs+deg2+cnt (adjacent)
  int* ip = (int*)fp;
  int* ctrs     = ip; ip += 8;                    // [0]=pscan ctr
  int* deg2     = ip; ip += Ntot;
  int* cnt      = ip; ip += Ntot;                 // fill cursors (relative)
  int* offs     = ip; ip += Ntot;
  int* partials = ip; ip += 512;
  ip = (int*)(((uintptr_t)ip + 15) & ~(uintptr_t)15);
  unsigned short* csr_col = (unsigned short*)ip;  // 2E ushorts

  const int G1    = (Ntot + 127) / 128;             // 782 chain/conv GEMM blocks
  const int scanB = (Ntot + 255) / 256;             // 391 (<=512 required)
  const int aggB  = Ntot / 4;                       // 25000 (Ntot % 4 == 0)
  const int degB  = ((E + 3) / 4 + 255) / 256;      // 782 per graph
  const int fillB = degB;

  // one memset: poolrep + ctrs + deg2 + cnt (adjacent)
  hipMemsetAsync(poolrep, 0, (16 * 256 + 8 + 2 * Ntot) * sizeof(float), stream);

  // D0: weight convert (all 4 matrices, frag order)
  k_wcvt<<<32, 256, 0, stream>>>(W_in[0], W_in[1], W_in[2], W_in[3], WfB);

  // D1: deg non-returning (1564 aux) || chained enc1+enc2 (782) -> bufA
  k_d1<<<2 * degB + G1, 256, 0, stream>>>(
      x1, x2, WfB, B_in[0], B_in[1], bufA, ei1, ei2, E, N, Ntot,
      deg2, G1, 2 * degB, degB);

  // D2: deg scan + dis (last block scans partials; 391 fences — measured OK)
  k_scan<<<scanB, 256, 0, stream>>>(deg2, offs, partials, dis, Ntot, scanB, ctrs);

  // D3: conv1 both (sparse, T1 scaled-fp8 -> bufT8) || fill both (returning cnt)
  k_conv1_fill<<<2 * fillB + G1, 256, 0, stream>>>(
      bufA, WfB + 2 * 16384, B_in[2], dis, bufT8, Ntot, G1,
      ei1, ei2, E, N, offs, partials, cnt, csr_col, fillB);

  // D4: aggregate 1 both graphs (bufT8 -> bufC f16); occupancy-critical, standalone
  k_agg<<<aggB, 256, 0, stream>>>(bufT8, offs, partials, csr_col, dis, bufC, N, Ntot, 2 * E);

  // D5: conv2 both graphs (T2 scaled-fp8 -> bufT8)
  k_gemm<<<G1, 256, 0, stream>>>(bufC, WfB + 3 * 16384, B_in[3], dis, bufT8, Ntot);

  // D6: aggregate 2 + pool both graphs (bufT8 -> poolrep); standalone
  k_agg_pool<<<aggB, 256, 0, stream>>>(bufT8, offs, partials, csr_col, dis, poolrep,
                                       N, Ntot, 2 * E);

  // D7: final MLP
  k_final<<<1, 128, 0, stream>>>(poolrep, sim_w1, sim_b1, sim_w2, sim_b2,
                                 (float*)d_out, 1.0f / (float)N);
}

// Round 14
// 380.942 us; speedup vs baseline: 1.1525x; 1.1525x over previous
//
#include <hip/hip_runtime.h>

#define HD 128  // hidden/feature dim (fixed by problem)
// fp8 e4m3 pre-scale: T1 rms ~2e-3, T2 rms ~8e-5 underflow e4m3's 2^-9 subnormal
// floor unscaled (round-12 failure). S=2^13 puts T1~16, T2~0.7 in normal range;
// clip at 448 = 27 sigma (never). Verified round 13: absmax 2.98e-8.
#define FP8_SCALE 8192.0f
#define FP8_INV   (1.0f / 8192.0f)

typedef _Float16 f16x8 __attribute__((ext_vector_type(8)));
typedef float f32x4 __attribute__((ext_vector_type(4)));
typedef float f32x2 __attribute__((ext_vector_type(2)));

static __device__ __forceinline__ unsigned char f32_to_fp8(float v) {
  return (unsigned char)(__builtin_amdgcn_cvt_pk_fp8_f32(v, v, 0, false) & 0xff);
}

// sparse role (role=1) occupies every k-th block: positions q*k, q<S.
__device__ __forceinline__ void role_map(int bi, int S, int k, int& role, int& rid) {
  int q = bi / k, rem = bi - q * k;
  if (rem == 0 && q < S) { role = 1; rid = q; }
  else { role = 0; int na = q + (rem ? 1 : 0); if (na > S) na = S; rid = bi - na; }
}

// ---------------- weight convert: fp32 [k][n] -> f16 MFMA-fragment order ----------
__global__ void k_wcvt(const float* __restrict__ w0, const float* __restrict__ w1,
                       const float* __restrict__ w2, const float* __restrict__ w3,
                       _Float16* __restrict__ Wf) {
  int m = blockIdx.x >> 3;
  const float* Wg = (m == 0) ? w0 : (m == 1) ? w1 : (m == 2) ? w2 : w3;
  int idx0 = (blockIdx.x & 7) * 2048 + threadIdx.x * 8;
  float4 u0 = *(const float4*)(Wg + idx0);
  float4 u1 = *(const float4*)(Wg + idx0 + 4);
  int k = idx0 >> 7, n0 = idx0 & 127;
  int kc = k >> 5, q2 = (k >> 3) & 3, j = k & 7;
  _Float16* dst = Wf + (size_t)m * 16384;
  float vv[8] = {u0.x, u0.y, u0.z, u0.w, u1.x, u1.y, u1.z, u1.w};
  #pragma unroll
  for (int d = 0; d < 8; ++d) {
    int n = n0 + d;
    dst[(size_t)(((n >> 4) * 4 + kc) * 64 + 16 * q2 + (n & 15)) * 8 + j] = (_Float16)vv[d];
  }
}

// ---------------- deg+slot role: returning atomics + slot record ------------------
// Round-13 lesson: D1's duration is ~90 us with returning OR non-returning atomics
// (chain GEMM + conflict rate dominate) — so take the returning+slot variant here,
// which makes the D3 fill atomic-free. Moving the returning atomic into D3 cost
// +35 us (round 13).
__device__ __forceinline__ void deg_core(int rid, int degB,
    const int* __restrict__ ei0, const int* __restrict__ ei1, int E, int N,
    int* __restrict__ deg2, unsigned short* __restrict__ slot) {
  int g = (rid >= degB);
  int cb = rid - g * degB;
  const int* rows = g ? ei1 : ei0;
  int* deg = deg2 + g * N;
  unsigned short* sl = slot + (size_t)g * E;
  int base = (cb * 256 + threadIdx.x) * 4;
  if (base + 3 < E) {
    int4 r = *(const int4*)(rows + base);
    union { unsigned short us[4]; uint2 v; } s;
    s.us[0] = (unsigned short)atomicAdd(&deg[r.x], 1);
    s.us[1] = (unsigned short)atomicAdd(&deg[r.y], 1);
    s.us[2] = (unsigned short)atomicAdd(&deg[r.z], 1);
    s.us[3] = (unsigned short)atomicAdd(&deg[r.w], 1);
    *(uint2*)(sl + base) = s.v;
  } else {
    for (int e = base; e < E; ++e)
      sl[e] = (unsigned short)atomicAdd(&deg[rows[e]], 1);
  }
}

// ---------------- CSR fill role: atomic-free scatter via slots --------------------
__device__ __forceinline__ void fill_core(int rid, int fillB,
    const int* __restrict__ ei0, const int* __restrict__ ei1, int E, int N,
    const int* __restrict__ offs, const int* __restrict__ partials,
    const unsigned short* __restrict__ slot, unsigned short* __restrict__ csr_col) {
  int g = (rid >= fillB);
  int cb = rid - g * fillB;
  const int* eg = (g ? ei1 : ei0);
  const int* ob = offs + g * N;
  const unsigned short* sl = slot + (size_t)g * E;
  int gN = g * N;
  int base = (cb * 256 + threadIdx.x) * 4;
  if (base + 3 < E) {
    int4 r = *(const int4*)(eg + base);
    int4 c = *(const int4*)(eg + E + base);
    uint2 sv = *(const uint2*)(sl + base);
    csr_col[ob[r.x] + partials[(gN + r.x) >> 8] + (sv.x & 0xffff)] = (unsigned short)c.x;
    csr_col[ob[r.y] + partials[(gN + r.y) >> 8] + (sv.x >> 16)]    = (unsigned short)c.y;
    csr_col[ob[r.z] + partials[(gN + r.z) >> 8] + (sv.y & 0xffff)] = (unsigned short)c.z;
    csr_col[ob[r.w] + partials[(gN + r.w) >> 8] + (sv.y >> 16)]    = (unsigned short)c.w;
  } else {
    for (int e = base; e < E; ++e)
      csr_col[ob[eg[e]] + partials[(gN + eg[e]) >> 8] + sl[e]] = (unsigned short)eg[E + e];
  }
}

// ---------------- GEMM role: C = (A @ Wfrag + b) * dis[row]; scaled-fp8 out -------
__device__ __forceinline__ void gemm_core(_Float16* lds, int bi,
    const _Float16* __restrict__ Ab, const _Float16* __restrict__ Wf,
    const float* __restrict__ bias, const float* __restrict__ scale,
    unsigned char* __restrict__ Cv, int Ntot) {
  const int tid = threadIdx.x;
  #pragma unroll
  for (int i = 0; i < 8; ++i)
    *(float4*)&lds[tid * 8 + i * 2048] = *(const float4*)&Wf[tid * 8 + i * 2048];
  __syncthreads();

  const int lane = tid & 63, wave = tid >> 6;
  const int n16 = lane & 15, q = lane >> 4;
  const int rowbase = bi * 128 + wave * 32;

  int arow[2];
  #pragma unroll
  for (int t = 0; t < 2; ++t) {
    int r = rowbase + 16 * t + n16;
    arow[t] = (r < Ntot) ? r : (Ntot - 1);
  }
  f32x4 acc[2][8];
  #pragma unroll
  for (int t = 0; t < 2; ++t)
    #pragma unroll
    for (int nt = 0; nt < 8; ++nt) acc[t][nt] = (f32x4){0.f, 0.f, 0.f, 0.f};

  #pragma unroll
  for (int kc = 0; kc < 4; ++kc) {
    f16x8 a[2];
    #pragma unroll
    for (int t = 0; t < 2; ++t)
      a[t] = *(const f16x8*)(Ab + (size_t)arow[t] * HD + kc * 32 + q * 8);
    #pragma unroll
    for (int nt = 0; nt < 8; ++nt) {
      f16x8 b = *(const f16x8*)&lds[(size_t)((nt * 4 + kc) * 64 + lane) * 8];
      #pragma unroll
      for (int t = 0; t < 2; ++t)
        acc[t][nt] = __builtin_amdgcn_mfma_f32_16x16x32_f16(a[t], b, acc[t][nt], 0, 0, 0);
    }
  }
  float bv[8];
  #pragma unroll
  for (int nt = 0; nt < 8; ++nt) bv[nt] = bias[nt * 16 + n16];
  #pragma unroll
  for (int t = 0; t < 2; ++t) {
    #pragma unroll
    for (int r = 0; r < 4; ++r) {
      int row = rowbase + 16 * t + 4 * q + r;
      if (row < Ntot) {
        float s = scale[row];
        #pragma unroll
        for (int nt = 0; nt < 8; ++nt) {
          float v = (acc[t][nt][r] + bv[nt]) * s;
          Cv[(size_t)row * HD + nt * 16 + n16] = f32_to_fp8(v * FP8_SCALE);
        }
      }
    }
  }
}

// ---------------- chained enc1+enc2 (row-local; act via wave-private LDS) ---------
__device__ __forceinline__ void chain_core(_Float16* act, int bi,
    const float* __restrict__ x0, const float* __restrict__ x1,
    const _Float16* __restrict__ Wf0, const _Float16* __restrict__ Wf1,
    const float* __restrict__ b1, const float* __restrict__ b2,
    _Float16* __restrict__ H, int N, int Ntot) {
  const int tid = threadIdx.x;
  const int lane = tid & 63, wave = tid >> 6;
  const int n16 = lane & 15, q = lane >> 4;
  const int rowbase = bi * 128 + wave * 32;
  _Float16* wact = act + wave * 4352;   // 32 rows x 136 f16

  int arow[2];
  #pragma unroll
  for (int t = 0; t < 2; ++t) {
    int r = rowbase + 16 * t + n16;
    arow[t] = (r < Ntot) ? r : (Ntot - 1);
  }
  f32x4 acc[2][8];
  #pragma unroll
  for (int t = 0; t < 2; ++t)
    #pragma unroll
    for (int nt = 0; nt < 8; ++nt) acc[t][nt] = (f32x4){0.f, 0.f, 0.f, 0.f};

  // layer 1: x -> relu(x@W1+b1) -> wave-private LDS
  #pragma unroll
  for (int kc = 0; kc < 4; ++kc) {
    f16x8 a[2];
    #pragma unroll
    for (int t = 0; t < 2; ++t) {
      int r = arow[t];
      const float* src = (r < N) ? (x0 + (size_t)r * HD) : (x1 + (size_t)(r - N) * HD);
      float4 u0 = *(const float4*)(src + kc * 32 + q * 8);
      float4 u1 = *(const float4*)(src + kc * 32 + q * 8 + 4);
      union { _Float16 h[8]; f16x8 v; } tmp;
      tmp.h[0] = (_Float16)u0.x; tmp.h[1] = (_Float16)u0.y;
      tmp.h[2] = (_Float16)u0.z; tmp.h[3] = (_Float16)u0.w;
      tmp.h[4] = (_Float16)u1.x; tmp.h[5] = (_Float16)u1.y;
      tmp.h[6] = (_Float16)u1.z; tmp.h[7] = (_Float16)u1.w;
      a[t] = tmp.v;
    }
    #pragma unroll
    for (int nt = 0; nt < 8; ++nt) {
      f16x8 b = *(const f16x8*)&Wf0[(size_t)((nt * 4 + kc) * 64 + lane) * 8];
      #pragma unroll
      for (int t = 0; t < 2; ++t)
        acc[t][nt] = __builtin_amdgcn_mfma_f32_16x16x32_f16(a[t], b, acc[t][nt], 0, 0, 0);
    }
  }
  {
    float bv[8];
    #pragma unroll
    for (int nt = 0; nt < 8; ++nt) bv[nt] = b1[nt * 16 + n16];
    #pragma unroll
    for (int t = 0; t < 2; ++t)
      #pragma unroll
      for (int r = 0; r < 4; ++r)
        #pragma unroll
        for (int nt = 0; nt < 8; ++nt)
          wact[(16 * t + 4 * q + r) * 136 + nt * 16 + n16] =
              (_Float16)fmaxf(acc[t][nt][r] + bv[nt], 0.f);
  }

  // layer 2: h1 -> h1@W2+b2 (no relu)
  #pragma unroll
  for (int t = 0; t < 2; ++t)
    #pragma unroll
    for (int nt = 0; nt < 8; ++nt) acc[t][nt] = (f32x4){0.f, 0.f, 0.f, 0.f};
  #pragma unroll
  for (int kc = 0; kc < 4; ++kc) {
    f16x8 a[2];
    #pragma unroll
    for (int t = 0; t < 2; ++t)
      a[t] = *(const f16x8*)&wact[(16 * t + n16) * 136 + kc * 32 + q * 8];
    #pragma unroll
    for (int nt = 0; nt < 8; ++nt) {
      f16x8 b = *(const f16x8*)&Wf1[(size_t)((nt * 4 + kc) * 64 + lane) * 8];
      #pragma unroll
      for (int t = 0; t < 2; ++t)
        acc[t][nt] = __builtin_amdgcn_mfma_f32_16x16x32_f16(a[t], b, acc[t][nt], 0, 0, 0);
    }
  }
  {
    float bv[8];
    #pragma unroll
    for (int nt = 0; nt < 8; ++nt) bv[nt] = b2[nt * 16 + n16];
    #pragma unroll
    for (int t = 0; t < 2; ++t)
      #pragma unroll
      for (int r = 0; r < 4; ++r) {
        int row = rowbase + 16 * t + 4 * q + r;
        if (row < Ntot)
          #pragma unroll
          for (int nt = 0; nt < 8; ++nt)
            H[(size_t)row * HD + nt * 16 + n16] = (_Float16)(acc[t][nt][r] + bv[nt]);
      }
  }
}

// ---------------- aggregate core (scaled fp8 T): out = relu(dis/S * sum T) --------
template<bool POOL>
__device__ __forceinline__ void agg_core(float* red, int rid,
    const unsigned char* __restrict__ T8, const int* __restrict__ offs,
    const int* __restrict__ partials, const unsigned short* __restrict__ csr_col,
    const float* __restrict__ dis, _Float16* __restrict__ out,
    float* __restrict__ poolrep, int N, int Ntot, int Etot) {
  const int lane = threadIdx.x & 63;
  const int wave = threadIdx.x >> 6;
  const int gw = rid * 4 + wave;
  const int sub = lane >> 4, c16 = lane & 15;

  float ax[8];
  #pragma unroll
  for (int j = 0; j < 8; ++j) ax[j] = 0.f;

  const int beg = offs[gw] + partials[gw >> 8];
  const int end = (gw + 1 == Ntot) ? Etot : (offs[gw + 1] + partials[(gw + 1) >> 8]);
  const uint2* Tg = (const uint2*)(T8 + (size_t)(gw >= N ? N : 0) * HD);
  for (int e = beg; e < end; e += 16) {
    uint2 v[4];
    #pragma unroll
    for (int gp = 0; gp < 4; ++gp) {
      v[gp] = make_uint2(0, 0);            // fp8 0x00 == +0.0
      if (e + 4 * gp < end) {              // wave-uniform
        int eg = e + 4 * gp + sub;
        bool valid = (eg < end);
        int ce = valid ? eg : (end - 1);
        int col = csr_col[ce];
        uint2 tv = Tg[(size_t)col * 16 + c16];
        if (valid) v[gp] = tv;
      }
    }
    #pragma unroll
    for (int gp = 0; gp < 4; ++gp) {
      f32x2 p0 = __builtin_amdgcn_cvt_pk_f32_fp8((int)v[gp].x, false);
      f32x2 p1 = __builtin_amdgcn_cvt_pk_f32_fp8((int)v[gp].x, true);
      f32x2 p2 = __builtin_amdgcn_cvt_pk_f32_fp8((int)v[gp].y, false);
      f32x2 p3 = __builtin_amdgcn_cvt_pk_f32_fp8((int)v[gp].y, true);
      ax[0] += p0.x; ax[1] += p0.y;
      ax[2] += p1.x; ax[3] += p1.y;
      ax[4] += p2.x; ax[5] += p2.y;
      ax[6] += p3.x; ax[7] += p3.y;
    }
  }

  #pragma unroll
  for (int j = 0; j < 8; ++j) {
    ax[j] += __shfl_xor(ax[j], 32, 64);
    ax[j] += __shfl_xor(ax[j], 16, 64);
  }
  float dr = dis[gw] * FP8_INV;            // undo the fp8 pre-scale
  #pragma unroll
  for (int j = 0; j < 8; ++j) ax[j] = fmaxf(ax[j] * dr, 0.f);

  if (!POOL) {
    if (sub == 0) {                        // h1 stays f16 (feeds conv2 MFMA A)
      union { uint4 u; _Float16 h[8]; } o;
      #pragma unroll
      for (int j = 0; j < 8; ++j) o.h[j] = (_Float16)ax[j];
      ((uint4*)out)[(size_t)gw * 16 + c16] = o.u;
    }
  } else {
    if (sub == 0) {
      *(float4*)&red[wave * 128 + c16 * 8]     = make_float4(ax[0], ax[1], ax[2], ax[3]);
      *(float4*)&red[wave * 128 + c16 * 8 + 4] = make_float4(ax[4], ax[5], ax[6], ax[7]);
    }
    __syncthreads();
    int t = threadIdx.x;
    if (t < 128) {
      float s = red[t] + red[128 + t] + red[256 + t] + red[384 + t];
      int g = (rid * 4 >= N) ? 1 : 0;      // N % 4 == 0: block never spans graphs
      atomicAdd(&poolrep[(size_t)((rid & 15) * 2 + g) * 128 + t], s);
    }
  }
}

// ---------------- D1: deg_slot (returning) aux || chained enc1+enc2 ---------------
__global__ __launch_bounds__(256, 4) void k_d1(
    const float* __restrict__ x0, const float* __restrict__ x1,
    const _Float16* __restrict__ Wf, const float* __restrict__ b1,
    const float* __restrict__ b2, _Float16* __restrict__ H,
    const int* __restrict__ ei0, const int* __restrict__ ei1, int E, int N, int Ntot,
    int* __restrict__ deg2, unsigned short* __restrict__ slot, int G, int A, int degB) {
  __shared__ _Float16 act[4 * 4352];  // 34.8 KB
  int role, rid;
  role_map(blockIdx.x, G, (A + G) / G, role, rid);  // sparse = chain (every 3rd)
  if (role == 1)
    chain_core(act, rid, x0, x1, Wf, Wf + 16384, b1, b2, H, N, Ntot);
  else
    deg_core(rid, degB, ei0, ei1, E, N, deg2, slot);
}

// ---------------- D2: per-block deg scan + dis; last block scans partials ---------
__global__ __launch_bounds__(256, 2) void k_scan(
    const int* __restrict__ deg2, int* __restrict__ offs, int* __restrict__ partials,
    float* __restrict__ dis, int Ntot, int scanB, int* __restrict__ ctr) {
  __shared__ int s[512];
  __shared__ int lastFlag;
  int rid = blockIdx.x, t = threadIdx.x;
  int i = rid * 256 + t;
  int v = (i < Ntot) ? deg2[i] : 0;
  s[t] = v;
  __syncthreads();
  #pragma unroll
  for (int off = 1; off < 256; off <<= 1) {
    int x = (t >= off) ? s[t - off] : 0;
    __syncthreads();
    s[t] += x;
    __syncthreads();
  }
  if (i < Ntot) {
    offs[i] = s[t] - v;
    dis[i] = (v > 0) ? (1.0f / sqrtf((float)v)) : 0.0f;
  }
  if (t == 255) partials[rid] = s[255];
  __syncthreads();
  if (t == 0) {
    __threadfence();
    lastFlag = (atomicAdd(ctr, 1) == scanB - 1);
  }
  __syncthreads();
  if (lastFlag) {
    __threadfence();
    volatile int* vp = partials;
    int P = scanB;
    int v0 = (t < P) ? vp[t] : 0;
    int v1 = (t + 256 < P) ? vp[t + 256] : 0;
    __syncthreads();
    s[t] = v0;
    s[t + 256] = v1;
    __syncthreads();
    #pragma unroll
    for (int off = 1; off < 256; off <<= 1) {
      int x0 = (t >= off) ? s[t - off] : 0;
      int x1 = (t >= off) ? s[256 + t - off] : 0;
      __syncthreads();
      s[t] += x0;
      s[256 + t] += x1;
      __syncthreads();
    }
    int tot0 = s[255];
    if (t < P) partials[t] = s[t] - v0;
    if (t + 256 < P) partials[t + 256] = s[256 + t] + tot0 - v1;
  }
}

// ---------------- D3: conv1 both (sparse, scaled-fp8 out) || slot-based fill ------
__global__ __launch_bounds__(256, 4) void k_conv1_fill(
    const _Float16* __restrict__ Ain, const _Float16* __restrict__ Wf,
    const float* __restrict__ bias, const float* __restrict__ dis,
    unsigned char* __restrict__ Cout, int Ntot, int G,
    const int* __restrict__ ei0, const int* __restrict__ ei1, int E, int N,
    const int* __restrict__ offs, const int* __restrict__ partials,
    const unsigned short* __restrict__ slot, unsigned short* __restrict__ csr_col,
    int fillB) {
  __shared__ _Float16 lds[16384];
  int role, rid;
  role_map(blockIdx.x, G, 3, role, rid);  // sparse = gemm (2*fillB + G blocks, fillB==G)
  if (role == 1)
    gemm_core(lds, rid, Ain, Wf, bias, dis, Cout, Ntot);
  else
    fill_core(rid, fillB, ei0, ei1, E, N, offs, partials, slot, csr_col);
}

// ---------------- D4: aggregate both graphs (fp8 in, f16 out; high occ) -----------
__global__ __launch_bounds__(256) void k_agg(
    const unsigned char* __restrict__ T8, const int* __restrict__ offs,
    const int* __restrict__ partials, const unsigned short* __restrict__ csr_col,
    const float* __restrict__ dis, _Float16* __restrict__ out, int N, int Ntot, int Etot) {
  agg_core<false>(nullptr, blockIdx.x, T8, offs, partials, csr_col, dis,
                  out, nullptr, N, Ntot, Etot);
}

// ---------------- D5: conv2 GEMM both graphs (scaled-fp8 out, standalone) ---------
__global__ __launch_bounds__(256, 4) void k_gemm(
    const _Float16* __restrict__ Ain, const _Float16* __restrict__ Wf,
    const float* __restrict__ bias, const float* __restrict__ dis,
    unsigned char* __restrict__ Cout, int Ntot) {
  __shared__ _Float16 lds[16384];
  gemm_core(lds, blockIdx.x, Ain, Wf, bias, dis, Cout, Ntot);
}

// ---------------- D6: aggregate + pool both graphs (fp8 in; high occ) -------------
__global__ __launch_bounds__(256) void k_agg_pool(
    const unsigned char* __restrict__ T8, const int* __restrict__ offs,
    const int* __restrict__ partials, const unsigned short* __restrict__ csr_col,
    const float* __restrict__ dis, float* __restrict__ poolrep,
    int N, int Ntot, int Etot) {
  __shared__ float red[512];
  agg_core<true>(red, blockIdx.x, T8, offs, partials, csr_col, dis,
                 nullptr, poolrep, N, Ntot, Etot);
}

// ---------------- final similarity MLP (tiny, fp32) ----------------
__global__ void k_final(const float* __restrict__ poolrep,
                        const float* __restrict__ W1, const float* __restrict__ b1,
                        const float* __restrict__ W2, const float* __restrict__ b2,
                        float* __restrict__ out, float invN) {
  __shared__ float cs[512];
  __shared__ float red[2];
  int t = threadIdx.x;  // 128 threads
  float g1 = 0.f, g2 = 0.f;
  #pragma unroll
  for (int r = 0; r < 16; ++r) {
    g1 += poolrep[r * 256 + t];
    g2 += poolrep[r * 256 + 128 + t];
  }
  g1 *= invN;
  g2 *= invN;
  cs[t] = g1;
  cs[128 + t] = g2;
  cs[256 + t] = fabsf(g1 - g2);
  cs[384 + t] = g1 * g2;
  __syncthreads();
  float acc = b1[t];
  #pragma unroll 8
  for (int i = 0; i < 512; ++i) acc = fmaf(cs[i], W1[(size_t)i * HD + t], acc);
  float h = fmaxf(acc, 0.f);
  float v = h * W2[t];
  #pragma unroll
  for (int off = 32; off > 0; off >>= 1) v += __shfl_down(v, off, 64);
  if ((t & 63) == 0) red[t >> 6] = v;
  __syncthreads();
  if (t == 0) out[0] = red[0] + red[1] + b2[0];
}

extern "C" void kernel_launch(void* const* d_in, const int* in_sizes, int n_in,
                              void* d_out, int out_size, void* d_ws, size_t ws_size,
                              hipStream_t stream) {
  const float* x1     = (const float*)d_in[0];
  const int*   ei1    = (const int*)d_in[1];
  const float* x2     = (const float*)d_in[2];
  const int*   ei2    = (const int*)d_in[3];
  const float* W_in[4] = {(const float*)d_in[4], (const float*)d_in[6],
                          (const float*)d_in[8], (const float*)d_in[10]};
  const float* B_in[4] = {(const float*)d_in[5], (const float*)d_in[7],
                          (const float*)d_in[9], (const float*)d_in[11]};
  const float* sim_w1 = (const float*)d_in[12];
  const float* sim_b1 = (const float*)d_in[13];
  const float* sim_w2 = (const float*)d_in[14];
  const float* sim_b2 = (const float*)d_in[15];

  const int N = in_sizes[0] / HD;
  const int E = in_sizes[1] / 2;
  const int Ntot = 2 * N;

  // workspace layout (16B-aligned chunks first)
  _Float16* sp = (_Float16*)d_ws;
  _Float16* bufA = sp; sp += (size_t)Ntot * HD;   // H (enc out)
  _Float16* bufC = sp; sp += (size_t)Ntot * HD;   // h1 (agg1 out)
  unsigned char* bufT8 = (unsigned char*)sp;      // T1 then T2 (scaled fp8)
  sp += (size_t)Ntot * HD / 2;
  _Float16* WfB  = sp; sp += 4 * 16384;           // enc1,enc2,conv1,conv2 frag f16
  float* fp = (float*)sp;
  float* dis     = fp; fp += Ntot;
  float* poolrep = fp; fp += 16 * 256;            // zeroed with ctrs+deg2 (adjacent)
  int* ip = (int*)fp;
  int* ctrs     = ip; ip += 8;                    // [0]=pscan ctr
  int* deg2     = ip; ip += Ntot;
  int* offs     = ip; ip += Ntot;
  int* partials = ip; ip += 512;
  ip = (int*)(((uintptr_t)ip + 15) & ~(uintptr_t)15);
  unsigned short* slot = (unsigned short*)ip;       // 2E ushorts
  unsigned short* csr_col = slot + 2 * (size_t)E;   // 2E ushorts

  const int G1    = (Ntot + 127) / 128;             // 782 chain/conv GEMM blocks
  const int scanB = (Ntot + 255) / 256;             // 391 (<=512 required)
  const int aggB  = Ntot / 4;                       // 25000 (Ntot % 4 == 0)
  const int degB  = ((E + 3) / 4 + 255) / 256;      // 782 per graph
  const int fillB = degB;

  // one memset: poolrep + ctrs + deg2 (adjacent)
  hipMemsetAsync(poolrep, 0, (16 * 256 + 8 + Ntot) * sizeof(float), stream);

  // D0: weight convert (all 4 matrices, frag order)
  k_wcvt<<<32, 256, 0, stream>>>(W_in[0], W_in[1], W_in[2], W_in[3], WfB);

  // D1: deg_slot returning (1564 aux) || chained enc1+enc2 (782) -> bufA
  k_d1<<<2 * degB + G1, 256, 0, stream>>>(
      x1, x2, WfB, B_in[0], B_in[1], bufA, ei1, ei2, E, N, Ntot,
      deg2, slot, G1, 2 * degB, degB);

  // D2: deg scan + dis (last block scans partials; 391 fences — measured OK)
  k_scan<<<scanB, 256, 0, stream>>>(deg2, offs, partials, dis, Ntot, scanB, ctrs);

  // D3: conv1 both (sparse, T1 scaled-fp8 -> bufT8) || slot-based fill (atomic-free)
  k_conv1_fill<<<2 * fillB + G1, 256, 0, stream>>>(
      bufA, WfB + 2 * 16384, B_in[2], dis, bufT8, Ntot, G1,
      ei1, ei2, E, N, offs, partials, slot, csr_col, fillB);

  // D4: aggregate 1 both graphs (bufT8 -> bufC f16); occupancy-critical, standalone
  k_agg<<<aggB, 256, 0, stream>>>(bufT8, offs, partials, csr_col, dis, bufC, N, Ntot, 2 * E);

  // D5: conv2 both graphs (T2 scaled-fp8 -> bufT8)
  k_gemm<<<G1, 256, 0, stream>>>(bufC, WfB + 3 * 16384, B_in[3], dis, bufT8, Ntot);

  // D6: aggregate 2 + pool both graphs (bufT8 -> poolrep); standalone
  k_agg_pool<<<aggB, 256, 0, stream>>>(bufT8, offs, partials, csr_col, dis, poolrep,
                                       N, Ntot, 2 * E);

  // D7: final MLP
  k_final<<<1, 128, 0, stream>>>(poolrep, sim_w1, sim_b1, sim_w2, sim_b2,
                                 (float*)d_out, 1.0f / (float)N);
}